// Round 7
// baseline (164.380 us; speedup 1.0000x reference)
//
#include <hip/hip_runtime.h>
#include <math.h>

// CRF log-likelihood, B=2048, T=80, L=128 — v7: v6 + relaxed barrier.
// __syncthreads compiles to s_waitcnt vmcnt(0) lgkmcnt(0) + s_barrier, which
// drains the x-prefetch global loads into every step's critical path (the
// measured ~2100 cy/step wall). Replace with lgkmcnt-only drain + s_barrier
// (AITER-style): LDS double-buffer correctness preserved, global loads stay
// in flight. Also: MFMA dep-chain split 4 -> 2+2+add, exp(x) hoisted before
// the MFMA block (transcendental runs parallel to matrix pipe).

#define CRF_B 2048
#define CRF_T 80
#define CRF_L 128
#define R_REAL 4

typedef __attribute__((ext_vector_type(8))) short bf16x8_t;
typedef __attribute__((ext_vector_type(4))) float f32x4_t;

__device__ __forceinline__ int pack_bf16_trunc(float lo, float hi) {
    return (int)((__float_as_uint(lo) >> 16) | (__float_as_uint(hi) & 0xFFFF0000u));
}
__device__ __forceinline__ unsigned short bft(float f) {
    return (unsigned short)(__float_as_uint(f) >> 16);
}
__device__ __forceinline__ void lds_barrier() {
    // barrier that drains ONLY LDS ops — global prefetch stays outstanding
    asm volatile("s_waitcnt lgkmcnt(0)\n\ts_barrier" ::: "memory");
}

__global__ __launch_bounds__(256) void crf_v7_kernel(
    const float* __restrict__ x,           // [B,T,L]
    const float* __restrict__ trans,       // [L,L]
    const float* __restrict__ start_trans, // [L]
    const float* __restrict__ end_trans,   // [L]
    const int*   __restrict__ y,           // [B,T]
    float* __restrict__ out)               // [B]
{
    const int tid  = threadIdx.x;
    const int w    = tid >> 6;     // wave 0..3: owns states [32w, 32w+32)
    const int lane = tid & 63;
    const int quad = lane >> 4;
    const int n16  = lane & 15;    // tile row; real batch row = row0 + (n16&3)
    const int row0 = blockIdx.x * R_REAL;
    const int brow = row0 + (n16 & (R_REAL - 1));

    __shared__ __attribute__((aligned(16))) short Vb[2][16][136]; // bf16 V, dbuf
    __shared__ __attribute__((aligned(16))) float maxb[16][4];    // [row][wave]
    __shared__ __attribute__((aligned(16))) float sumb[16][4];
    __shared__ float numb[R_REAL];

    // ---------------- numerator: wave w -> real row row0+w ----------------
    {
        const int bb = row0 + w;
        const int* yb = y + bb * CRF_T;
        const float* xbn = x + (size_t)bb * CRF_T * CRF_L;
        float p = 0.f;
        for (int t = lane; t < CRF_T; t += 64) {
            const int yt = yb[t];
            p += xbn[t * CRF_L + yt];
            p += (t + 1 < CRF_T) ? trans[yt * CRF_L + yb[t + 1]] : end_trans[yt];
            if (t == 0) p += start_trans[yt];
        }
        #pragma unroll
        for (int off = 1; off <= 32; off <<= 1) p += __shfl_xor(p, off);
        if (lane == 0) numb[w] = p;
    }

    // ---------- A-frags: E^T in registers. A[m][k] = exp(trans[k][m]) ----------
    bf16x8_t Af[2][4];
    #pragma unroll
    for (int mt = 0; mt < 2; ++mt) {
        const int m = 32 * w + 16 * mt + n16;  // global output state
        #pragma unroll
        for (int kk = 0; kk < 4; ++kk) {
            union { bf16x8_t v; unsigned short s[8]; } u;
            #pragma unroll
            for (int j = 0; j < 8; ++j) {
                const int k = 32 * kk + 8 * quad + j;  // input state
                u.s[j] = bft(__expf(trans[k * CRF_L + m]));
            }
            Af[mt][kk] = u.v;
        }
    }

    const int sc0 = 32 * w + 4 * quad;
    const int sc1 = sc0 + 16;
    const float* xr = x + (size_t)brow * CRF_T * CRF_L;

    f32x4_t ex_end[2], st4[2];
    {
        const f32x4_t e0 = *(const f32x4_t*)&end_trans[sc0];
        const f32x4_t e1 = *(const f32x4_t*)&end_trans[sc1];
        #pragma unroll
        for (int r = 0; r < 4; ++r) {
            ex_end[0][r] = __expf(e0[r]);
            ex_end[1][r] = __expf(e1[r]);
        }
        st4[0] = *(const f32x4_t*)&start_trans[sc0];
        st4[1] = *(const f32x4_t*)&start_trans[sc1];
    }

    f32x4_t P[2];
    float invM = 1.f, crun = 0.f;
    f32x4_t xc[2], xn[2];
    xc[0] = *(const f32x4_t*)&xr[sc0];
    xc[1] = *(const f32x4_t*)&xr[sc1];

    for (int t = 0; t < CRF_T; ++t) {
        // prefetch next step's emissions (global; stays in flight across barrier)
        if (t + 1 < CRF_T) {
            xn[0] = *(const f32x4_t*)&xr[(t + 1) * CRF_L + sc0];
            xn[1] = *(const f32x4_t*)&xr[(t + 1) * CRF_L + sc1];
        }

        // delayed renorm: consume maxb written at step t-1 (t = 4,8,...,76)
        const bool ap = (t > 0) && ((t & 3) == 0);
        if (ap) {
            const f32x4_t mb = *(const f32x4_t*)&maxb[n16][0];
            const float M = fmaxf(fmaxf(mb[0], mb[1]), fmaxf(mb[2], mb[3]));
            crun += __logf(M);
            invM  = __builtin_amdgcn_rcpf(M);
        }

        if (t == 0) {
            #pragma unroll
            for (int r = 0; r < 4; ++r) {
                P[0][r] = __expf(st4[0][r] + xc[0][r]);
                P[1][r] = __expf(st4[1][r] + xc[1][r]);
            }
        } else {
            // exp(x)*invM FIRST: transcendental overlaps the MFMA chain below
            float e[2][4];
            #pragma unroll
            for (int mt = 0; mt < 2; ++mt)
            #pragma unroll
            for (int r = 0; r < 4; ++r) {
                float ev = __expf(xc[mt][r]);
                if (ap) ev *= invM;
                e[mt][r] = ev;
            }

            // B-frags: V^T from LDS. B[k][n]: n = n16, k = 32kk+8quad+j
            const short* vrow = &Vb[(t - 1) & 1][n16][0];
            bf16x8_t Bf[4];
            #pragma unroll
            for (int kk = 0; kk < 4; ++kk)
                Bf[kk] = *(const bf16x8_t*)&vrow[32 * kk + 8 * quad];

            #pragma unroll
            for (int mt = 0; mt < 2; ++mt) {
                // two independent 2-chains, then add: halves dependent latency
                f32x4_t a0 = {0.f, 0.f, 0.f, 0.f};
                f32x4_t a1 = {0.f, 0.f, 0.f, 0.f};
                a0 = __builtin_amdgcn_mfma_f32_16x16x32_bf16(Af[mt][0], Bf[0], a0, 0, 0, 0);
                a1 = __builtin_amdgcn_mfma_f32_16x16x32_bf16(Af[mt][1], Bf[1], a1, 0, 0, 0);
                a0 = __builtin_amdgcn_mfma_f32_16x16x32_bf16(Af[mt][2], Bf[2], a0, 0, 0, 0);
                a1 = __builtin_amdgcn_mfma_f32_16x16x32_bf16(Af[mt][3], Bf[3], a1, 0, 0, 0);
                #pragma unroll
                for (int r = 0; r < 4; ++r)
                    P[mt][r] = (a0[r] + a1[r]) * e[mt][r];
            }
        }

        // every 4th step: per-row max across this wave's 32 states -> maxb
        if (((t & 3) == 3) && (t < CRF_T - 1)) {
            float g = fmaxf(fmaxf(fmaxf(P[0][0], P[0][1]), fmaxf(P[0][2], P[0][3])),
                            fmaxf(fmaxf(P[1][0], P[1][1]), fmaxf(P[1][2], P[1][3])));
            g = fmaxf(g, __shfl_xor(g, 16));
            g = fmaxf(g, __shfl_xor(g, 32));
            if (lane < 16) maxb[n16][w] = g;
        }

        if (t < CRF_T - 1) {
            // write V_t (bf16 trunc) to the other buffer
            short* dst = &Vb[t & 1][n16][0];
            const int d00 = pack_bf16_trunc(P[0][0], P[0][1]);
            const int d01 = pack_bf16_trunc(P[0][2], P[0][3]);
            const int d10 = pack_bf16_trunc(P[1][0], P[1][1]);
            const int d11 = pack_bf16_trunc(P[1][2], P[1][3]);
            *(int2*)&dst[sc0] = make_int2(d00, d01);
            *(int2*)&dst[sc1] = make_int2(d10, d11);
            lds_barrier();   // drains LDS only — x prefetch stays outstanding
        }

        xc[0] = xn[0];
        xc[1] = xn[1];
    }

    // ------------- epilogue: log_z = crun + log(sum_s P[s]*exp(end[s])) -------------
    float sv = 0.f;
    #pragma unroll
    for (int mt = 0; mt < 2; ++mt)
    #pragma unroll
    for (int r = 0; r < 4; ++r)
        sv += P[mt][r] * ex_end[mt][r];
    sv += __shfl_xor(sv, 16);
    sv += __shfl_xor(sv, 32);
    if (lane < 16) sumb[n16][w] = sv;
    __syncthreads();
    if (tid < R_REAL) {
        const f32x4_t sb = *(const f32x4_t*)&sumb[tid][0];
        const float S = sb[0] + sb[1] + sb[2] + sb[3];
        out[row0 + tid] = numb[tid] - (crun + __logf(S));
    }
}

extern "C" void kernel_launch(void* const* d_in, const int* in_sizes, int n_in,
                              void* d_out, int out_size, void* d_ws, size_t ws_size,
                              hipStream_t stream) {
    const float* x     = (const float*)d_in[0];
    const float* trans = (const float*)d_in[1];
    const float* st    = (const float*)d_in[2];
    const float* et    = (const float*)d_in[3];
    const int*   y     = (const int*)d_in[4];
    float* out = (float*)d_out;

    crf_v7_kernel<<<CRF_B / R_REAL, 256, 0, stream>>>(x, trans, st, et, y, out);
}

// Round 8
// 157.037 us; speedup vs baseline: 1.0468x; 1.0468x over previous
//
#include <hip/hip_runtime.h>
#include <math.h>

// CRF log-likelihood, B=2048, T=80, L=128 — v8: meet-in-the-middle on the
// v6 LDS structure. fwd chain a_t (t=1..39) and bwd chain v_t (t=78..40)
// run INTERLEAVED in the same wave: independent dep chains fill each
// other's latency shadows and the serial step count halves (80 -> 40).
//   fwd: a_t = exp(x_t) o (E^T a_{t-1}),  a_0  = exp(start + x_0)
//   bwd: v_t = exp(x_t) o (E   v_{t+1}),  v_79 = exp(end   + x_79)
//   Z = a_39^T · E · v_40   (one extra MFMA + cross-wave dot)
// Per direction: A-frags = 32 VGPRs/wave (E^T resp. E) -> ~180 VGPR total,
// no spill, 2 blocks/CU. Renorm every 4 pair-steps, one-step-delayed apply.

#define CRF_B 2048
#define CRF_T 80
#define CRF_L 128
#define R_REAL 4

typedef __attribute__((ext_vector_type(8))) short bf16x8_t;
typedef __attribute__((ext_vector_type(4))) float f32x4_t;

__device__ __forceinline__ int pack_bf16_trunc(float lo, float hi) {
    return (int)((__float_as_uint(lo) >> 16) | (__float_as_uint(hi) & 0xFFFF0000u));
}
__device__ __forceinline__ unsigned short bft(float f) {
    return (unsigned short)(__float_as_uint(f) >> 16);
}

__global__ __launch_bounds__(256, 2) void crf_v8_kernel(
    const float* __restrict__ x,           // [B,T,L]
    const float* __restrict__ trans,       // [L,L]
    const float* __restrict__ start_trans, // [L]
    const float* __restrict__ end_trans,   // [L]
    const int*   __restrict__ y,           // [B,T]
    float* __restrict__ out)               // [B]
{
    const int tid  = threadIdx.x;
    const int w    = tid >> 6;     // wave 0..3: owns states [32w, 32w+32)
    const int lane = tid & 63;
    const int quad = lane >> 4;
    const int n16  = lane & 15;    // tile row; real batch row = row0 + (n16&3)
    const int row0 = blockIdx.x * R_REAL;
    const int brow = row0 + (n16 & (R_REAL - 1));

    __shared__ __attribute__((aligned(16))) short VbF[2][16][136];
    __shared__ __attribute__((aligned(16))) short VbB[2][16][136];
    __shared__ __attribute__((aligned(16))) float maxbF[16][4];
    __shared__ __attribute__((aligned(16))) float maxbB[16][4];
    __shared__ __attribute__((aligned(16))) float sumb[16][4];
    __shared__ float numb[R_REAL];

    // ---------------- numerator: wave w -> real row row0+w ----------------
    {
        const int bb = row0 + w;
        const int* yb = y + bb * CRF_T;
        const float* xbn = x + (size_t)bb * CRF_T * CRF_L;
        float p = 0.f;
        for (int t = lane; t < CRF_T; t += 64) {
            const int yt = yb[t];
            p += xbn[t * CRF_L + yt];
            p += (t + 1 < CRF_T) ? trans[yt * CRF_L + yb[t + 1]] : end_trans[yt];
            if (t == 0) p += start_trans[yt];
        }
        #pragma unroll
        for (int off = 1; off <= 32; off <<= 1) p += __shfl_xor(p, off);
        if (lane == 0) numb[w] = p;
    }

    // ---------------- A-frags: fwd = E^T, bwd = E (32 VGPR each) ----------------
    // A layout: lane(q,n16) holds A[m-frag = n16][k = 32kk + 8q + j];
    // global m state = 32w + 16mt + n16, global k state = 32kk + 8q + j.
    bf16x8_t AfF[2][4], AfB[2][4];
    #pragma unroll
    for (int mt = 0; mt < 2; ++mt) {
        const int m = 32 * w + 16 * mt + n16;
        #pragma unroll
        for (int kk = 0; kk < 4; ++kk) {
            union { bf16x8_t v; unsigned short s[8]; } uF, uB;
            #pragma unroll
            for (int j = 0; j < 8; ++j) {
                const int k = 32 * kk + 8 * quad + j;
                uF.s[j] = bft(__expf(trans[k * CRF_L + m]));
                uB.s[j] = bft(__expf(trans[m * CRF_L + k]));
            }
            AfF[mt][kk] = uF.v;
            AfB[mt][kk] = uB.v;
        }
    }

    const int sc0 = 32 * w + 4 * quad;
    const int sc1 = sc0 + 16;
    const float* xr = x + (size_t)brow * CRF_T * CRF_L;

    f32x4_t PF[2], PB[2];
    float invF = 1.f, crunF = 0.f, invB = 1.f, crunB = 0.f;

    // ---------------- init: a_0 and v_79, pack into buffer 0 ----------------
    {
        const f32x4_t st0 = *(const f32x4_t*)&start_trans[sc0];
        const f32x4_t st1 = *(const f32x4_t*)&start_trans[sc1];
        const f32x4_t en0 = *(const f32x4_t*)&end_trans[sc0];
        const f32x4_t en1 = *(const f32x4_t*)&end_trans[sc1];
        const f32x4_t xf0 = *(const f32x4_t*)&xr[0 * CRF_L + sc0];
        const f32x4_t xf1 = *(const f32x4_t*)&xr[0 * CRF_L + sc1];
        const f32x4_t xb0 = *(const f32x4_t*)&xr[79 * CRF_L + sc0];
        const f32x4_t xb1 = *(const f32x4_t*)&xr[79 * CRF_L + sc1];
        #pragma unroll
        for (int r = 0; r < 4; ++r) {
            PF[0][r] = __expf(st0[r] + xf0[r]);
            PF[1][r] = __expf(st1[r] + xf1[r]);
            PB[0][r] = __expf(en0[r] + xb0[r]);
            PB[1][r] = __expf(en1[r] + xb1[r]);
        }
        short* dF = &VbF[0][n16][0];
        short* dB = &VbB[0][n16][0];
        *(int2*)&dF[sc0] = make_int2(pack_bf16_trunc(PF[0][0], PF[0][1]),
                                     pack_bf16_trunc(PF[0][2], PF[0][3]));
        *(int2*)&dF[sc1] = make_int2(pack_bf16_trunc(PF[1][0], PF[1][1]),
                                     pack_bf16_trunc(PF[1][2], PF[1][3]));
        *(int2*)&dB[sc0] = make_int2(pack_bf16_trunc(PB[0][0], PB[0][1]),
                                     pack_bf16_trunc(PB[0][2], PB[0][3]));
        *(int2*)&dB[sc1] = make_int2(pack_bf16_trunc(PB[1][0], PB[1][1]),
                                     pack_bf16_trunc(PB[1][2], PB[1][3]));
        __syncthreads();
    }

    // current emissions: fwd t=1, bwd t=78
    f32x4_t xfc[2], xbc[2], xfn[2], xbn[2];
    xfc[0] = *(const f32x4_t*)&xr[1 * CRF_L + sc0];
    xfc[1] = *(const f32x4_t*)&xr[1 * CRF_L + sc1];
    xbc[0] = *(const f32x4_t*)&xr[78 * CRF_L + sc0];
    xbc[1] = *(const f32x4_t*)&xr[78 * CRF_L + sc1];

    // ---------------- pair-steps k = 1..39 (fwd t=k, bwd t=79-k) ----------------
    for (int k = 1; k <= 39; ++k) {
        if (k < 39) {   // prefetch next pair's emissions
            xfn[0] = *(const f32x4_t*)&xr[(k + 1) * CRF_L + sc0];
            xfn[1] = *(const f32x4_t*)&xr[(k + 1) * CRF_L + sc1];
            xbn[0] = *(const f32x4_t*)&xr[(78 - k) * CRF_L + sc0];
            xbn[1] = *(const f32x4_t*)&xr[(78 - k) * CRF_L + sc1];
        }

        // delayed renorm apply (k = 4, 8, ..., 36)
        const bool ap = (k & 3) == 0;
        if (ap) {
            const f32x4_t mF = *(const f32x4_t*)&maxbF[n16][0];
            const f32x4_t mB = *(const f32x4_t*)&maxbB[n16][0];
            const float MF = fmaxf(fmaxf(mF[0], mF[1]), fmaxf(mF[2], mF[3]));
            const float MB = fmaxf(fmaxf(mB[0], mB[1]), fmaxf(mB[2], mB[3]));
            crunF += __logf(MF);  invF = __builtin_amdgcn_rcpf(MF);
            crunB += __logf(MB);  invB = __builtin_amdgcn_rcpf(MB);
        }

        // exp first: transcendental overlaps the MFMA chains below
        float eF[2][4], eB[2][4];
        #pragma unroll
        for (int mt = 0; mt < 2; ++mt)
        #pragma unroll
        for (int r = 0; r < 4; ++r) {
            float vF = __expf(xfc[mt][r]);
            float vB = __expf(xbc[mt][r]);
            if (ap) { vF *= invF; vB *= invB; }
            eF[mt][r] = vF;
            eB[mt][r] = vB;
        }

        // B-frags for both chains from LDS
        const short* vrF = &VbF[(k - 1) & 1][n16][0];
        const short* vrB = &VbB[(k - 1) & 1][n16][0];
        bf16x8_t BfF[4], BfB[4];
        #pragma unroll
        for (int kk = 0; kk < 4; ++kk) {
            BfF[kk] = *(const bf16x8_t*)&vrF[32 * kk + 8 * quad];
            BfB[kk] = *(const bf16x8_t*)&vrB[32 * kk + 8 * quad];
        }

        // two independent MFMA chains (fwd/bwd interleaved by the scheduler)
        #pragma unroll
        for (int mt = 0; mt < 2; ++mt) {
            f32x4_t aF = {0.f, 0.f, 0.f, 0.f};
            f32x4_t aB = {0.f, 0.f, 0.f, 0.f};
            #pragma unroll
            for (int kk = 0; kk < 4; ++kk) {
                aF = __builtin_amdgcn_mfma_f32_16x16x32_bf16(AfF[mt][kk], BfF[kk], aF, 0, 0, 0);
                aB = __builtin_amdgcn_mfma_f32_16x16x32_bf16(AfB[mt][kk], BfB[kk], aB, 0, 0, 0);
            }
            #pragma unroll
            for (int r = 0; r < 4; ++r) {
                PF[mt][r] = aF[r] * eF[mt][r];
                PB[mt][r] = aB[r] * eB[mt][r];
            }
        }

        // renorm max compute (k = 3, 7, ..., 35)
        if (((k & 3) == 3) && (k < 39)) {
            float gF = PF[0][0], gB = PB[0][0];
            #pragma unroll
            for (int mt = 0; mt < 2; ++mt)
            #pragma unroll
            for (int r = 0; r < 4; ++r) {
                gF = fmaxf(gF, PF[mt][r]);
                gB = fmaxf(gB, PB[mt][r]);
            }
            gF = fmaxf(gF, __shfl_xor(gF, 16)); gF = fmaxf(gF, __shfl_xor(gF, 32));
            gB = fmaxf(gB, __shfl_xor(gB, 16)); gB = fmaxf(gB, __shfl_xor(gB, 32));
            if (lane < 16) { maxbF[n16][w] = gF; maxbB[n16][w] = gB; }
        }

        if (k < 39) {
            short* dF = &VbF[k & 1][n16][0];
            short* dB = &VbB[k & 1][n16][0];
            *(int2*)&dF[sc0] = make_int2(pack_bf16_trunc(PF[0][0], PF[0][1]),
                                         pack_bf16_trunc(PF[0][2], PF[0][3]));
            *(int2*)&dF[sc1] = make_int2(pack_bf16_trunc(PF[1][0], PF[1][1]),
                                         pack_bf16_trunc(PF[1][2], PF[1][3]));
            *(int2*)&dB[sc0] = make_int2(pack_bf16_trunc(PB[0][0], PB[0][1]),
                                         pack_bf16_trunc(PB[0][2], PB[0][3]));
            *(int2*)&dB[sc1] = make_int2(pack_bf16_trunc(PB[1][0], PB[1][1]),
                                         pack_bf16_trunc(PB[1][2], PB[1][3]));
        } else {
            // k = 39: only v_40 needs the LDS round-trip (for the combine MFMA)
            short* dB = &VbB[1][n16][0];
            *(int2*)&dB[sc0] = make_int2(pack_bf16_trunc(PB[0][0], PB[0][1]),
                                         pack_bf16_trunc(PB[0][2], PB[0][3]));
            *(int2*)&dB[sc1] = make_int2(pack_bf16_trunc(PB[1][0], PB[1][1]),
                                         pack_bf16_trunc(PB[1][2], PB[1][3]));
        }
        __syncthreads();

        xfc[0] = xfn[0]; xfc[1] = xfn[1];
        xbc[0] = xbn[0]; xbc[1] = xbn[1];
    }

    // ---------------- combine: ww = E · v_40 ; Z = a_39 · ww ----------------
    float sv = 0.f;
    {
        const short* vrB = &VbB[1][n16][0];
        bf16x8_t BfB[4];
        #pragma unroll
        for (int kk = 0; kk < 4; ++kk)
            BfB[kk] = *(const bf16x8_t*)&vrB[32 * kk + 8 * quad];
        #pragma unroll
        for (int mt = 0; mt < 2; ++mt) {
            f32x4_t aW = {0.f, 0.f, 0.f, 0.f};
            #pragma unroll
            for (int kk = 0; kk < 4; ++kk)
                aW = __builtin_amdgcn_mfma_f32_16x16x32_bf16(AfB[mt][kk], BfB[kk], aW, 0, 0, 0);
            #pragma unroll
            for (int r = 0; r < 4; ++r)
                sv += PF[mt][r] * aW[r];
        }
    }
    sv += __shfl_xor(sv, 16);
    sv += __shfl_xor(sv, 32);
    if (lane < 16) sumb[n16][w] = sv;
    __syncthreads();
    if (tid < R_REAL) {
        const f32x4_t sb = *(const f32x4_t*)&sumb[tid][0];
        const float S = sb[0] + sb[1] + sb[2] + sb[3];
        out[row0 + tid] = numb[tid] - (crunF + crunB + __logf(S));
    }
}

extern "C" void kernel_launch(void* const* d_in, const int* in_sizes, int n_in,
                              void* d_out, int out_size, void* d_ws, size_t ws_size,
                              hipStream_t stream) {
    const float* x     = (const float*)d_in[0];
    const float* trans = (const float*)d_in[1];
    const float* st    = (const float*)d_in[2];
    const float* et    = (const float*)d_in[3];
    const int*   y     = (const int*)d_in[4];
    float* out = (float*)d_out;

    crf_v8_kernel<<<CRF_B / R_REAL, 256, 0, stream>>>(x, trans, st, et, y, out);
}